// Round 1
// baseline (35.990 us; speedup 1.0000x reference)
//
#include <hip/hip_runtime.h>
#include <math.h>

#define NP 196
#define KP 4
#define NCLS 10

__global__ __launch_bounds__(256) void quanv_fused_kernel(
    const float* __restrict__ x,    // [B,1,28,28] -> [B,784]
    const float* __restrict__ phi,  // [B,196,4]
    const float* __restrict__ W,    // [10,784]
    const float* __restrict__ bl,   // [10]
    float* __restrict__ out)        // [B,10]
{
    const int b = blockIdx.x;
    const int t = threadIdx.x;

    __shared__ float4 e_s[NP];        // expvals per patch
    __shared__ float4 n_s[NP];        // normalized states
    __shared__ float  feat_s[NP * KP]; // smoothed, flattened [784]
    __shared__ float  logit_s[NCLS];

    // ---- Phase 1: patches -> expvals -> normalized ----
    if (t < NP) {
        const int hp = t / 14, wp = t % 14;
        const float* xb = x + (size_t)b * 784;
        const int r0 = hp * 2, c0 = wp * 2;
        float th0 = xb[(r0 + 0) * 28 + c0 + 0];
        float th1 = xb[(r0 + 0) * 28 + c0 + 1];
        float th2 = xb[(r0 + 1) * 28 + c0 + 0];
        float th3 = xb[(r0 + 1) * 28 + c0 + 1];
        float4 ph = *(const float4*)(phi + (size_t)b * (NP * KP) + t * 4);
        float z0 = cosf(th0) * cosf(ph.x);
        float z1 = cosf(th1) * cosf(ph.y);
        float z2 = cosf(th2) * cosf(ph.z);
        float z3 = cosf(th3) * cosf(ph.w);
        float e0 = z0;
        float e1 = e0 * z1;
        float e2 = e1 * z2;
        float e3 = e2 * z3;
        e_s[t] = make_float4(e0, e1, e2, e3);
        float nn = sqrtf(e0 * e0 + e1 * e1 + e2 * e2 + e3 * e3) + 1e-12f;
        float inv = 1.0f / nn;
        n_s[t] = make_float4(e0 * inv, e1 * inv, e2 * inv, e3 * inv);
    }
    __syncthreads();

    // ---- Phase 2: pairwise fidelity graph + smoothing ----
    if (t < NP) {
        const float4 q = n_s[t];
        const float4 e = e_s[t];
        float a0 = 0.f, a1 = 0.f, a2 = 0.f, a3 = 0.f, deg = 0.f;
        for (int m = 0; m < NP; ++m) {
            float4 nm = n_s[m];   // wave-uniform m -> LDS broadcast
            float4 em = e_s[m];
            float d = q.x * nm.x + q.y * nm.y + q.z * nm.z + q.w * nm.w;
            float fid = d * d;
            float w = (fid >= 0.8f) ? 1.0f : ((fid >= 0.5f) ? 0.5f : 0.0f);
            if (m == t) w = 0.f;   // no self-edges
            deg += w;
            a0 += w * em.x; a1 += w * em.y; a2 += w * em.z; a3 += w * em.w;
        }
        const float s = 1.0f + deg;   // smooth = I + D - W
        feat_s[t * 4 + 0] = s * e.x - a0;
        feat_s[t * 4 + 1] = s * e.y - a1;
        feat_s[t * 4 + 2] = s * e.z - a2;
        feat_s[t * 4 + 3] = s * e.w - a3;
    }
    __syncthreads();

    // ---- Phase 3: logits = feats @ W^T + b, 10 groups x 16 lanes ----
    if (t < NCLS * 16) {
        const int j = t >> 4;      // class
        const int s = t & 15;      // lane within group
        const float* wr = W + j * (NP * KP);
        float p = 0.f;
        for (int i = s; i < NP * KP; i += 16)
            p += feat_s[i] * wr[i];
        for (int off = 8; off > 0; off >>= 1)
            p += __shfl_down(p, off, 16);
        if (s == 0) logit_s[j] = p + bl[j];
    }
    __syncthreads();

    // ---- Phase 4: log_softmax ----
    if (t < NCLS) {
        float mx = -INFINITY;
        #pragma unroll
        for (int j = 0; j < NCLS; ++j) mx = fmaxf(mx, logit_s[j]);
        float sum = 0.f;
        #pragma unroll
        for (int j = 0; j < NCLS; ++j) sum += expf(logit_s[j] - mx);
        out[(size_t)b * NCLS + t] = logit_s[t] - mx - logf(sum);
    }
}

extern "C" void kernel_launch(void* const* d_in, const int* in_sizes, int n_in,
                              void* d_out, int out_size, void* d_ws, size_t ws_size,
                              hipStream_t stream) {
    const float* x   = (const float*)d_in[0];   // [B,1,28,28]
    const float* phi = (const float*)d_in[1];   // [B,196,4]
    const float* W   = (const float*)d_in[2];   // [10,784]
    const float* bl  = (const float*)d_in[3];   // [10]
    float* out = (float*)d_out;                 // [B,10]

    const int B = in_sizes[0] / 784;
    quanv_fused_kernel<<<dim3(B), dim3(256), 0, stream>>>(x, phi, W, bl, out);
}

// Round 3
// 27.698 us; speedup vs baseline: 1.2994x; 1.2994x over previous
//
#include <hip/hip_runtime.h>
#include <math.h>

#define NP 196
#define NCLS 10

// Block = 128 threads (2 waves), one image per block.
//  Phase 1: all 128 threads compute expvals e[196] (float4) + inv[196] -> LDS.
//  Phase 2: lane<49 owns 4 patches n = lane+49k; wave w iterates m in [98w,98w+98).
//           fid = (e_n . e_m)^2 * inv2_n * inv2_m  (no normalized vectors needed).
//           Self-edge removed by exact post-subtraction (same formula/bits).
//  Phase 3: wave 1 dumps partial (a,deg) to LDS; wave 0 combines, builds feats
//           in registers, dots against W (L2-hot float4 loads), butterfly-reduce.
//  Phase 4: lane 0 does log_softmax and stores 10 outputs.
__global__ __launch_bounds__(128) void quanv_fused_kernel(
    const float* __restrict__ x,    // [B,784]
    const float* __restrict__ phi,  // [B,196,4]
    const float* __restrict__ W,    // [10,784]
    const float* __restrict__ bl,   // [10]
    float* __restrict__ out)        // [B,10]
{
    const int b    = blockIdx.x;
    const int t    = threadIdx.x;
    const int wave = t >> 6;
    const int lane = t & 63;

    __shared__ float4 e_s[NP];      // expvals
    __shared__ float  inv_s[NP];    // 1/(||e||+1e-12)
    __shared__ float4 ap_s[49 * 4]; // wave-1 partial a
    __shared__ float  dp_s[49 * 4]; // wave-1 partial deg

    const float* xb = x + (size_t)b * 784;
    const float* pb = phi + (size_t)b * 784;

    // ---- Phase 1 ----
    for (int p = t; p < NP; p += 128) {
        const int hp = p / 14, wp = p - hp * 14;
        const int r0 = hp * 2, c0 = wp * 2;
        float th0 = xb[r0 * 28 + c0];
        float th1 = xb[r0 * 28 + c0 + 1];
        float th2 = xb[(r0 + 1) * 28 + c0];
        float th3 = xb[(r0 + 1) * 28 + c0 + 1];
        float4 ph = *(const float4*)(pb + p * 4);
        float z0 = cosf(th0) * cosf(ph.x);
        float z1 = cosf(th1) * cosf(ph.y);
        float z2 = cosf(th2) * cosf(ph.z);
        float z3 = cosf(th3) * cosf(ph.w);
        float e0 = z0;
        float e1 = e0 * z1;
        float e2 = e1 * z2;
        float e3 = e2 * z3;
        e_s[p] = make_float4(e0, e1, e2, e3);
        float nn = sqrtf(e0 * e0 + e1 * e1 + e2 * e2 + e3 * e3) + 1e-12f;
        inv_s[p] = 1.0f / nn;
    }
    __syncthreads();

    // ---- Phase 2 ----
    float4 q[4];
    float  inv2[4];
    float4 a[4];
    float  deg[4];
    #pragma unroll
    for (int k = 0; k < 4; ++k) {
        a[k] = make_float4(0.f, 0.f, 0.f, 0.f);
        deg[k] = 0.f;
    }

    if (lane < 49) {
        #pragma unroll
        for (int k = 0; k < 4; ++k) {
            const int n = lane + 49 * k;
            q[k] = e_s[n];
            float iv = inv_s[n];
            inv2[k] = iv * iv;
        }
        const int m0 = wave * 98;
        for (int m = m0; m < m0 + 98; ++m) {
            float4 em = e_s[m];          // wave-uniform broadcast read
            float ivm = inv_s[m];
            float im2 = ivm * ivm;
            #pragma unroll
            for (int k = 0; k < 4; ++k) {
                float d   = q[k].x * em.x + q[k].y * em.y + q[k].z * em.z + q[k].w * em.w;
                float fid = (d * d) * (inv2[k] * im2);
                float w   = (fid >= 0.8f) ? 1.0f : ((fid >= 0.5f) ? 0.5f : 0.0f);
                deg[k] += w;
                a[k].x += w * em.x;
                a[k].y += w * em.y;
                a[k].z += w * em.z;
                a[k].w += w * em.w;
            }
        }
    }

    if (wave == 1 && lane < 49) {
        #pragma unroll
        for (int k = 0; k < 4; ++k) {
            ap_s[lane * 4 + k] = a[k];
            dp_s[lane * 4 + k] = deg[k];
        }
    }
    __syncthreads();

    float pj[NCLS];
    #pragma unroll
    for (int j = 0; j < NCLS; ++j) pj[j] = 0.f;

    if (wave == 0 && lane < 49) {
        float4 f[4];
        #pragma unroll
        for (int k = 0; k < 4; ++k) {
            float4 ap = ap_s[lane * 4 + k];
            float  dp = dp_s[lane * 4 + k];
            a[k].x += ap.x; a[k].y += ap.y; a[k].z += ap.z; a[k].w += ap.w;
            deg[k] += dp;
            // exact self-edge subtraction (mirrors loop-iteration arithmetic)
            float d   = q[k].x * q[k].x + q[k].y * q[k].y + q[k].z * q[k].z + q[k].w * q[k].w;
            float fid = (d * d) * (inv2[k] * inv2[k]);
            float w   = (fid >= 0.8f) ? 1.0f : ((fid >= 0.5f) ? 0.5f : 0.0f);
            deg[k] -= w;
            a[k].x -= w * q[k].x;
            a[k].y -= w * q[k].y;
            a[k].z -= w * q[k].z;
            a[k].w -= w * q[k].w;
            const float s = 1.0f + deg[k];   // smooth = I + D - W
            f[k].x = s * q[k].x - a[k].x;
            f[k].y = s * q[k].y - a[k].y;
            f[k].z = s * q[k].z - a[k].z;
            f[k].w = s * q[k].w - a[k].w;
        }
        // ---- Phase 3: per-lane partial logits ----
        #pragma unroll
        for (int j = 0; j < NCLS; ++j) {
            const float* wr = W + j * 784;
            float p = 0.f;
            #pragma unroll
            for (int k = 0; k < 4; ++k) {
                const int n = lane + 49 * k;
                float4 w4 = *(const float4*)(wr + n * 4);
                p += f[k].x * w4.x + f[k].y * w4.y + f[k].z * w4.z + f[k].w * w4.w;
            }
            pj[j] = p;
        }
    }

    if (wave == 0) {
        // butterfly reduce over 64 lanes (lanes 49-63 contribute zeros)
        #pragma unroll
        for (int j = 0; j < NCLS; ++j) {
            float v = pj[j];
            #pragma unroll
            for (int off = 32; off > 0; off >>= 1)
                v += __shfl_xor(v, off, 64);
            pj[j] = v;
        }
        if (lane == 0) {
            float lg[NCLS];
            float mx = -INFINITY;
            #pragma unroll
            for (int j = 0; j < NCLS; ++j) {
                lg[j] = pj[j] + bl[j];
                mx = fmaxf(mx, lg[j]);
            }
            float sum = 0.f;
            #pragma unroll
            for (int j = 0; j < NCLS; ++j) sum += expf(lg[j] - mx);
            const float ls = logf(sum);
            #pragma unroll
            for (int j = 0; j < NCLS; ++j)
                out[(size_t)b * NCLS + j] = lg[j] - mx - ls;
        }
    }
}

extern "C" void kernel_launch(void* const* d_in, const int* in_sizes, int n_in,
                              void* d_out, int out_size, void* d_ws, size_t ws_size,
                              hipStream_t stream) {
    const float* x   = (const float*)d_in[0];   // [B,1,28,28]
    const float* phi = (const float*)d_in[1];   // [B,196,4]
    const float* W   = (const float*)d_in[2];   // [10,784]
    const float* bl  = (const float*)d_in[3];   // [10]
    float* out = (float*)d_out;                 // [B,10]

    const int B = in_sizes[0] / 784;
    quanv_fused_kernel<<<dim3(B), dim3(128), 0, stream>>>(x, phi, W, bl, out);
}

// Round 4
// 27.100 us; speedup vs baseline: 1.3281x; 1.0221x over previous
//
#include <hip/hip_runtime.h>
#include <math.h>

#define NP 196
#define NCLS 10

// Block = 256 threads (4 waves), one image per block, grid = B = 1024.
// 4 blocks/CU -> 16 waves/CU = 4/SIMD.
//  Phase 1 : t<196 computes expvals e[t] (float4), inv, inv^2 -> LDS.
//  Phase 2 : wave w handles m in [49w, 49w+49); lane<49 owns patches n=lane+49k.
//            qn = e_n * inv_n pre-normalized; fid = (qn . e_m)^2 * inv2_m.
//            Partial (a, deg) per wave -> LDS.
//  Phase 2b: t<196 combines 4 partials, removes self-edge (mirrors loop
//            arithmetic exactly), builds feats float4 -> LDS.
//  Phase 3 : t<160: class j=t>>4, slice s=t&15 dots feat x W (float4, L2-hot),
//            16-lane shfl reduce -> logit_s.
//  Phase 4 : t<10 computes log_softmax, stores out[b,10].
__global__ __launch_bounds__(256) void quanv_fused_kernel(
    const float* __restrict__ x,    // [B,784]
    const float* __restrict__ phi,  // [B,196,4]
    const float* __restrict__ W,    // [10,784]
    const float* __restrict__ bl,   // [10]
    float* __restrict__ out)        // [B,10]
{
    const int b    = blockIdx.x;
    const int t    = threadIdx.x;
    const int wave = t >> 6;
    const int lane = t & 63;

    __shared__ float4 e_s[NP];
    __shared__ float  inv_s[NP];
    __shared__ float  inv2_s[NP];
    __shared__ float4 pa_s[4 * NP];
    __shared__ float  pd_s[4 * NP];
    __shared__ float4 feat_s[NP];
    __shared__ float  logit_s[NCLS];

    const float* xb = x + (size_t)b * 784;
    const float* pb = phi + (size_t)b * 784;

    // ---- Phase 1 ----
    if (t < NP) {
        const int hp = t / 14, wp = t - hp * 14;
        const int r0 = hp * 2, c0 = wp * 2;
        float th0 = xb[r0 * 28 + c0];
        float th1 = xb[r0 * 28 + c0 + 1];
        float th2 = xb[(r0 + 1) * 28 + c0];
        float th3 = xb[(r0 + 1) * 28 + c0 + 1];
        float4 ph = *(const float4*)(pb + t * 4);
        float z0 = cosf(th0) * cosf(ph.x);
        float z1 = cosf(th1) * cosf(ph.y);
        float z2 = cosf(th2) * cosf(ph.z);
        float z3 = cosf(th3) * cosf(ph.w);
        float e0 = z0;
        float e1 = e0 * z1;
        float e2 = e1 * z2;
        float e3 = e2 * z3;
        e_s[t] = make_float4(e0, e1, e2, e3);
        float nn = sqrtf(e0 * e0 + e1 * e1 + e2 * e2 + e3 * e3) + 1e-12f;
        float iv = 1.0f / nn;
        inv_s[t]  = iv;
        inv2_s[t] = iv * iv;
    }
    __syncthreads();

    // ---- Phase 2 ----
    if (lane < 49) {
        float4 qn[4];
        float4 a[4];
        float  deg[4];
        #pragma unroll
        for (int k = 0; k < 4; ++k) {
            const int n = lane + 49 * k;
            float4 q = e_s[n];
            float iv = inv_s[n];
            qn[k] = make_float4(q.x * iv, q.y * iv, q.z * iv, q.w * iv);
            a[k] = make_float4(0.f, 0.f, 0.f, 0.f);
            deg[k] = 0.f;
        }
        const int m0 = wave * 49;
        for (int m = m0; m < m0 + 49; ++m) {
            float4 em  = e_s[m];     // wave-uniform broadcast
            float  im2 = inv2_s[m];
            #pragma unroll
            for (int k = 0; k < 4; ++k) {
                float d   = qn[k].x * em.x + qn[k].y * em.y + qn[k].z * em.z + qn[k].w * em.w;
                float fid = (d * d) * im2;
                float w   = (fid >= 0.8f) ? 1.0f : ((fid >= 0.5f) ? 0.5f : 0.0f);
                deg[k] += w;
                a[k].x += w * em.x;
                a[k].y += w * em.y;
                a[k].z += w * em.z;
                a[k].w += w * em.w;
            }
        }
        #pragma unroll
        for (int k = 0; k < 4; ++k) {
            pa_s[wave * NP + lane + 49 * k] = a[k];
            pd_s[wave * NP + lane + 49 * k] = deg[k];
        }
    }
    __syncthreads();

    // ---- Phase 2b: combine partials, self-subtract, build feats ----
    if (t < NP) {
        float4 e  = e_s[t];
        float  iv = inv_s[t];
        float  i2 = inv2_s[t];
        float4 at = make_float4(0.f, 0.f, 0.f, 0.f);
        float  dt = 0.f;
        #pragma unroll
        for (int w = 0; w < 4; ++w) {
            float4 p = pa_s[w * NP + t];
            at.x += p.x; at.y += p.y; at.z += p.z; at.w += p.w;
            dt += pd_s[w * NP + t];
        }
        // self-edge: mirror the loop-iteration arithmetic for m == n
        float4 qnn = make_float4(e.x * iv, e.y * iv, e.z * iv, e.w * iv);
        float d    = qnn.x * e.x + qnn.y * e.y + qnn.z * e.z + qnn.w * e.w;
        float fid  = (d * d) * i2;
        float w    = (fid >= 0.8f) ? 1.0f : ((fid >= 0.5f) ? 0.5f : 0.0f);
        dt -= w;
        at.x -= w * e.x; at.y -= w * e.y; at.z -= w * e.z; at.w -= w * e.w;
        const float s = 1.0f + dt;   // smooth = I + D - W
        feat_s[t] = make_float4(s * e.x - at.x, s * e.y - at.y,
                                s * e.z - at.z, s * e.w - at.w);
    }
    __syncthreads();

    // ---- Phase 3: logits ----
    if (t < NCLS * 16) {
        const int j  = t >> 4;
        const int sl = t & 15;
        const float4* wr = (const float4*)(W + j * 784);
        float p = 0.f;
        for (int i = sl; i < NP; i += 16) {
            float4 f  = feat_s[i];
            float4 w4 = wr[i];
            p += f.x * w4.x + f.y * w4.y + f.z * w4.z + f.w * w4.w;
        }
        #pragma unroll
        for (int off = 8; off > 0; off >>= 1)
            p += __shfl_down(p, off, 16);
        if (sl == 0) logit_s[j] = p + bl[j];
    }
    __syncthreads();

    // ---- Phase 4: log_softmax ----
    if (t < NCLS) {
        float mx = -INFINITY;
        #pragma unroll
        for (int j = 0; j < NCLS; ++j) mx = fmaxf(mx, logit_s[j]);
        float sum = 0.f;
        #pragma unroll
        for (int j = 0; j < NCLS; ++j) sum += expf(logit_s[j] - mx);
        out[(size_t)b * NCLS + t] = logit_s[t] - mx - logf(sum);
    }
}

extern "C" void kernel_launch(void* const* d_in, const int* in_sizes, int n_in,
                              void* d_out, int out_size, void* d_ws, size_t ws_size,
                              hipStream_t stream) {
    const float* x   = (const float*)d_in[0];   // [B,1,28,28]
    const float* phi = (const float*)d_in[1];   // [B,196,4]
    const float* W   = (const float*)d_in[2];   // [10,784]
    const float* bl  = (const float*)d_in[3];   // [10]
    float* out = (float*)d_out;                 // [B,10]

    const int B = in_sizes[0] / 784;
    quanv_fused_kernel<<<dim3(B), dim3(256), 0, stream>>>(x, phi, W, bl, out);
}

// Round 5
// 23.720 us; speedup vs baseline: 1.5173x; 1.1425x over previous
//
#include <hip/hip_runtime.h>
#include <math.h>

#define NP 196
#define NCLS 10

// Block = 256 threads (4 waves), one image per block, grid = B = 1024.
//  Phase 1 : t<196 computes expvals e[t] (float4) via fast __cosf, inv,
//            and sqrt-scaled thresholds (sh,sl) = (sqrt(.8),sqrt(.5))*||e|| -> LDS.
//  Phase 2 : wave w handles m in [49w,49w+49); lane<49 owns patches n=lane+49k.
//            qn = e_n * inv_n; edge test: |qn . e_m| >= sh_m / sl_m
//            (algebraically == fid thresholds, no d^2 or inv^2 muls in loop).
//  Phase 2b: t<196 combines 4 wave-partials, removes self-edge (mirrors loop
//            arithmetic), builds feats float4 -> LDS.
//  Phase 3 : t<160: class j=t>>4, slice s=t&15 dots feat x W (float4, L2-hot),
//            16-lane shfl reduce -> logits.
//  Phase 4 : t<10 computes log_softmax, stores out[b,10].
__global__ __launch_bounds__(256) void quanv_fused_kernel(
    const float* __restrict__ x,    // [B,784]
    const float* __restrict__ phi,  // [B,196,4]
    const float* __restrict__ W,    // [10,784]
    const float* __restrict__ bl,   // [10]
    float* __restrict__ out)        // [B,10]
{
    const int b    = blockIdx.x;
    const int t    = threadIdx.x;
    const int wave = t >> 6;
    const int lane = t & 63;

    __shared__ float4 e_s[NP];      // expvals
    __shared__ float  inv_s[NP];    // 1/(||e||+1e-12)
    __shared__ float2 thr_s[NP];    // (sqrt(0.8)*nm, sqrt(0.5)*nm)
    __shared__ float4 pa_s[4 * NP]; // per-wave partial a
    __shared__ float  pd_s[4 * NP]; // per-wave partial deg
    __shared__ float4 feat_s[NP];
    __shared__ float  logit_s[NCLS];

    const float* xb = x + (size_t)b * 784;
    const float* pb = phi + (size_t)b * 784;

    // ---- Phase 1 ----
    if (t < NP) {
        const int hp = t / 14, wp = t - hp * 14;
        const int r0 = hp * 2, c0 = wp * 2;
        float th0 = xb[r0 * 28 + c0];
        float th1 = xb[r0 * 28 + c0 + 1];
        float th2 = xb[(r0 + 1) * 28 + c0];
        float th3 = xb[(r0 + 1) * 28 + c0 + 1];
        float4 ph = *(const float4*)(pb + t * 4);
        float z0 = __cosf(th0) * __cosf(ph.x);
        float z1 = __cosf(th1) * __cosf(ph.y);
        float z2 = __cosf(th2) * __cosf(ph.z);
        float z3 = __cosf(th3) * __cosf(ph.w);
        float e0 = z0;
        float e1 = e0 * z1;
        float e2 = e1 * z2;
        float e3 = e2 * z3;
        e_s[t] = make_float4(e0, e1, e2, e3);
        float nn = sqrtf(e0 * e0 + e1 * e1 + e2 * e2 + e3 * e3) + 1e-12f;
        inv_s[t] = 1.0f / nn;
        thr_s[t] = make_float2(0.8944271909999159f * nn,   // sqrt(0.8)*nm
                               0.7071067811865476f * nn);  // sqrt(0.5)*nm
    }
    __syncthreads();

    // ---- Phase 2 ----
    if (lane < 49) {
        float4 qn[4];
        float4 a[4];
        float  deg[4];
        #pragma unroll
        for (int k = 0; k < 4; ++k) {
            const int n = lane + 49 * k;
            float4 q = e_s[n];
            float iv = inv_s[n];
            qn[k] = make_float4(q.x * iv, q.y * iv, q.z * iv, q.w * iv);
            a[k] = make_float4(0.f, 0.f, 0.f, 0.f);
            deg[k] = 0.f;
        }
        const int m0 = wave * 49;
        #pragma unroll 7
        for (int m = m0; m < m0 + 49; ++m) {
            float4 em = e_s[m];      // wave-uniform broadcast
            float2 th = thr_s[m];
            #pragma unroll
            for (int k = 0; k < 4; ++k) {
                float d  = qn[k].x * em.x + qn[k].y * em.y + qn[k].z * em.z + qn[k].w * em.w;
                float ad = fabsf(d);  // free input modifier on v_cmp
                float w  = (ad >= th.x) ? 1.0f : ((ad >= th.y) ? 0.5f : 0.0f);
                deg[k] += w;
                a[k].x += w * em.x;
                a[k].y += w * em.y;
                a[k].z += w * em.z;
                a[k].w += w * em.w;
            }
        }
        #pragma unroll
        for (int k = 0; k < 4; ++k) {
            pa_s[wave * NP + lane + 49 * k] = a[k];
            pd_s[wave * NP + lane + 49 * k] = deg[k];
        }
    }
    __syncthreads();

    // ---- Phase 2b: combine partials, self-subtract, build feats ----
    if (t < NP) {
        float4 e  = e_s[t];
        float  iv = inv_s[t];
        float2 th = thr_s[t];
        float4 at = make_float4(0.f, 0.f, 0.f, 0.f);
        float  dt = 0.f;
        #pragma unroll
        for (int w = 0; w < 4; ++w) {
            float4 p = pa_s[w * NP + t];
            at.x += p.x; at.y += p.y; at.z += p.z; at.w += p.w;
            dt += pd_s[w * NP + t];
        }
        // self-edge: mirror the loop-iteration arithmetic for m == n
        float4 qnn = make_float4(e.x * iv, e.y * iv, e.z * iv, e.w * iv);
        float d   = qnn.x * e.x + qnn.y * e.y + qnn.z * e.z + qnn.w * e.w;
        float ad  = fabsf(d);
        float w   = (ad >= th.x) ? 1.0f : ((ad >= th.y) ? 0.5f : 0.0f);
        dt -= w;
        at.x -= w * e.x; at.y -= w * e.y; at.z -= w * e.z; at.w -= w * e.w;
        const float s = 1.0f + dt;   // smooth = I + D - W
        feat_s[t] = make_float4(s * e.x - at.x, s * e.y - at.y,
                                s * e.z - at.z, s * e.w - at.w);
    }
    __syncthreads();

    // ---- Phase 3: logits ----
    if (t < NCLS * 16) {
        const int j  = t >> 4;
        const int sl = t & 15;
        const float4* wr = (const float4*)(W + j * 784);
        float p = 0.f;
        for (int i = sl; i < NP; i += 16) {
            float4 f  = feat_s[i];
            float4 w4 = wr[i];
            p += f.x * w4.x + f.y * w4.y + f.z * w4.z + f.w * w4.w;
        }
        #pragma unroll
        for (int off = 8; off > 0; off >>= 1)
            p += __shfl_down(p, off, 16);
        if (sl == 0) logit_s[j] = p + bl[j];
    }
    __syncthreads();

    // ---- Phase 4: log_softmax ----
    if (t < NCLS) {
        float mx = -INFINITY;
        #pragma unroll
        for (int j = 0; j < NCLS; ++j) mx = fmaxf(mx, logit_s[j]);
        float sum = 0.f;
        #pragma unroll
        for (int j = 0; j < NCLS; ++j) sum += expf(logit_s[j] - mx);
        out[(size_t)b * NCLS + t] = logit_s[t] - mx - logf(sum);
    }
}

extern "C" void kernel_launch(void* const* d_in, const int* in_sizes, int n_in,
                              void* d_out, int out_size, void* d_ws, size_t ws_size,
                              hipStream_t stream) {
    const float* x   = (const float*)d_in[0];   // [B,1,28,28]
    const float* phi = (const float*)d_in[1];   // [B,196,4]
    const float* W   = (const float*)d_in[2];   // [10,784]
    const float* bl  = (const float*)d_in[3];   // [10]
    float* out = (float*)d_out;                 // [B,10]

    const int B = in_sizes[0] / 784;
    quanv_fused_kernel<<<dim3(B), dim3(256), 0, stream>>>(x, phi, W, bl, out);
}